// Round 5
// baseline (91.292 us; speedup 1.0000x reference)
//
#include <hip/hip_runtime.h>
#include <hip/hip_bf16.h>

typedef __attribute__((ext_vector_type(8))) short short8;
typedef __attribute__((ext_vector_type(4))) float f32x4;
typedef float f4a __attribute__((ext_vector_type(4), aligned(4)));  // align-4 float4

constexpr int NF = 169;
constexpr int NH = 128;

#define MFMA(a, b, c) __builtin_amdgcn_mfma_f32_16x16x32_bf16(a, b, c, 0, 0, 0)

__device__ inline unsigned short f2bf(float f) {
    union { __hip_bfloat16 h; unsigned short u; } c;
    c.h = __float2bfloat16(f);
    return c.u;
}

__device__ inline short8 cvt8(f4a v0, f4a v1) {
    short8 p;
    p[0] = (short)f2bf(v0[0]); p[1] = (short)f2bf(v0[1]);
    p[2] = (short)f2bf(v0[2]); p[3] = (short)f2bf(v0[3]);
    p[4] = (short)f2bf(v1[0]); p[5] = (short)f2bf(v1[1]);
    p[6] = (short)f2bf(v1[2]); p[7] = (short)f2bf(v1[3]);
    return p;
}

// ZERO-__syncthreads design. Per-wave private 16 KB LDS arena:
//   [0, 8192)    pool [8 kg][64 rows][8] bf16   (dead after A1-frag reads)
//   [0, 16384)   h    [4 mt][16 kg][16 rows][8] bf16 (aliases pool; written after pool reads)
//   [mt*4096, +2704)  stage chunk [4 rows][169] f32 (aliases h[mt] after its A2 reads)
// Cross-lane visibility within a wave: in-order DS + s_waitcnt lgkmcnt(0) + wave_barrier.
// Only block-wide data (w1,b1,w2,b2) is read per-wave from global (L2-resident, tiny).
__global__ __launch_bounds__(256, 2) void fused_v5(
    const float* __restrict__ x,
    const float* __restrict__ w1,
    const float* __restrict__ b1,
    const float* __restrict__ w2,
    const float* __restrict__ b2,
    float* __restrict__ out)
{
    __shared__ __align__(16) char smem[65536];

    const int tid  = threadIdx.x;
    const int wid  = tid >> 6;
    const int lane = tid & 63;
    const int lr   = lane & 15;
    const int hi   = lane >> 4;

    char* arena = smem + wid * 16384;
    unsigned short* pool = (unsigned short*)arena;   // [8][64][8]
    unsigned short* hs   = (unsigned short*)arena;   // [4][16][16][8]

    const long rowBase = (long)blockIdx.x * 256 + wid * 64;

    // ================= per-thread pooling (row = rowBase + lane) =================
    const float* __restrict__ xr = x + (rowBase + lane) * NF;

    float f[169];
    #pragma unroll
    for (int i = 0; i < 42; ++i) {
        f4a v = *(const f4a*)(xr + i * 4);
        f[4*i+0] = v[0]; f[4*i+1] = v[1]; f[4*i+2] = v[2]; f[4*i+3] = v[3];
    }
    f[168] = xr[168];

    float pooled[36];
    #pragma unroll
    for (int i = 0; i < 6; ++i) {
        float cs[13];
        #pragma unroll
        for (int c = 0; c < 13; ++c) {
            float s = 0.0f;
            #pragma unroll
            for (int rr = 0; rr < 3; ++rr) {
                const int idx = (2 * i + rr) * 14 + c;   // compile-time
                if (idx < NF) s += f[idx];               // zero-pad region
            }
            cs[c] = s;
        }
        #pragma unroll
        for (int j = 0; j < 6; ++j) {
            const float s = cs[2*j] + cs[2*j+1] + cs[2*j+2];
            pooled[i * 6 + j] = fmaxf(s * (1.0f / 9.0f), 0.0f);
        }
    }

    // write pooled row (k zero-padded 36->64) into wave-private pool
    #pragma unroll
    for (int g = 0; g < 8; ++g) {
        short8 pk;
        #pragma unroll
        for (int j = 0; j < 8; ++j) {
            const int k = g * 8 + j;
            pk[j] = (k < 36) ? (short)f2bf(pooled[k]) : (short)0;
        }
        *(short8*)(pool + (g * 64 + lane) * 8) = pk;
    }
    asm volatile("s_waitcnt lgkmcnt(0)" ::: "memory");
    __builtin_amdgcn_wave_barrier();          // pool visible to all lanes of this wave

    // ================= A1 fragments (all 4 m-tiles, read before h overwrites pool) =================
    short8 af[4][2];
    #pragma unroll
    for (int mt = 0; mt < 4; ++mt)
        #pragma unroll
        for (int ks = 0; ks < 2; ++ks)
            af[mt][ks] = *(const short8*)(pool + ((ks * 4 + hi) * 64 + mt * 16 + lr) * 8);
    asm volatile("s_waitcnt lgkmcnt(0)" ::: "memory");
    __builtin_amdgcn_wave_barrier();          // pool reads complete before h writes

    // ================= GEMM1: h = relu(pooled @ w1^T + b1) -> wave-private h =================
    #pragma unroll
    for (int nt = 0; nt < 8; ++nt) {
        const int n = nt * 16 + lr;
        const float bias1 = b1[n];
        short8 bf[2];
        #pragma unroll
        for (int ks = 0; ks < 2; ++ks) {
            const int g = ks * 4 + hi;
            short8 pk = {0, 0, 0, 0, 0, 0, 0, 0};
            if (g < 4) {
                f4a v0 = *(const f4a*)(w1 + n * 36 + g * 8);
                f4a v1 = *(const f4a*)(w1 + n * 36 + g * 8 + 4);
                pk = cvt8(v0, v1);
            } else if (g == 4) {
                f4a v0 = *(const f4a*)(w1 + n * 36 + 32);   // k = 32..35
                pk[0] = (short)f2bf(v0[0]); pk[1] = (short)f2bf(v0[1]);
                pk[2] = (short)f2bf(v0[2]); pk[3] = (short)f2bf(v0[3]);
            }
            bf[ks] = pk;
        }
        #pragma unroll
        for (int mt = 0; mt < 4; ++mt) {
            f32x4 c = {0.f, 0.f, 0.f, 0.f};
            c = MFMA(af[mt][0], bf[0], c);
            c = MFMA(af[mt][1], bf[1], c);
            const int g2 = 2 * nt + (lr >> 3);
            const int e  = lr & 7;
            #pragma unroll
            for (int r = 0; r < 4; ++r) {
                const float v = fmaxf(c[r] + bias1, 0.0f);
                hs[mt * 2048 + (g2 * 16 + hi * 4 + r) * 8 + e] = f2bf(v);
            }
        }
    }
    asm volatile("s_waitcnt lgkmcnt(0)" ::: "memory");
    __builtin_amdgcn_wave_barrier();          // h visible

    // ================= w2 fragments + b2 (all 11 ot) to registers =================
    short8 wf[11][4];
    float  b2v[11];
    #pragma unroll
    for (int t = 0; t < 11; ++t) {
        const int o = t * 16 + lr;
        const bool valid = (t < 10) || (o < NF);
        b2v[t] = valid ? b2[o] : 0.0f;
        #pragma unroll
        for (int ks = 0; ks < 4; ++ks) {
            short8 pk = {0, 0, 0, 0, 0, 0, 0, 0};
            if (valid) {
                const float* wp = w2 + o * NH + ks * 32 + hi * 8;
                f4a v0 = *(const f4a*)(wp);
                f4a v1 = *(const f4a*)(wp + 4);
                pk = cvt8(v0, v1);
            }
            wf[t][ks] = pk;
        }
    }

    // ================= GEMM2 + wave-private staged coalesced stores =================
    #pragma unroll 1
    for (int mt = 0; mt < 4; ++mt) {
        f32x4 acc[11];
        #pragma unroll
        for (int t = 0; t < 11; ++t)
            acc[t] = (f32x4){b2v[t], b2v[t], b2v[t], b2v[t]};   // bias folded into init

        #pragma unroll
        for (int ks = 0; ks < 4; ++ks) {
            short8 a2 = *(const short8*)(hs + mt * 2048 + ((ks * 4 + hi) * 16 + lr) * 8);
            #pragma unroll
            for (int t = 0; t < 11; ++t)
                acc[t] = MFMA(a2, wf[t][ks], acc[t]);
        }

        float* buf = (float*)(arena + mt * 4096);   // [4 rows][169], aliases h[mt] (now dead)
        #pragma unroll
        for (int c = 0; c < 4; ++c) {
            if (hi == c) {                          // lanes hi==c own rows 4c..4c+3
                #pragma unroll
                for (int t = 0; t < 11; ++t) {
                    const int o = t * 16 + lr;
                    if (t < 10 || o < NF) {
                        #pragma unroll
                        for (int r = 0; r < 4; ++r)
                            buf[r * NF + o] = acc[t][r];
                    }
                }
            }
            asm volatile("s_waitcnt lgkmcnt(0)" ::: "memory");
            __builtin_amdgcn_wave_barrier();        // chunk staged

            float* op = out + (rowBase + mt * 16 + c * 4) * NF;
            #pragma unroll
            for (int it = 0; it < 3; ++it) {
                const int idx = lane + it * 64;
                if (idx < 169) {                    // 169 float4s = 4 rows x 169 f32
                    f32x4 v = *(const f32x4*)(buf + idx * 4);
                    *(f32x4*)(op + idx * 4) = v;
                }
            }
            asm volatile("s_waitcnt lgkmcnt(0)" ::: "memory");
            __builtin_amdgcn_wave_barrier();        // chunk reads done before next overwrite
        }
    }
}

extern "C" void kernel_launch(void* const* d_in, const int* in_sizes, int n_in,
                              void* d_out, int out_size, void* d_ws, size_t ws_size,
                              hipStream_t stream) {
    const float* x  = (const float*)d_in[0];
    const float* w1 = (const float*)d_in[1];
    const float* b1 = (const float*)d_in[2];
    const float* w2 = (const float*)d_in[3];
    const float* b2 = (const float*)d_in[4];
    float* out = (float*)d_out;

    const int rows = in_sizes[0] / NF;      // 131072
    const int blocks = rows / 256;          // 512
    fused_v5<<<blocks, 256, 0, stream>>>(x, w1, b1, w2, b2, out);
}

// Round 6
// 65.010 us; speedup vs baseline: 1.4043x; 1.4043x over previous
//
#include <hip/hip_runtime.h>
#include <hip/hip_bf16.h>

typedef __attribute__((ext_vector_type(8))) short short8;
typedef __attribute__((ext_vector_type(4))) float f32x4;
typedef float f4a __attribute__((ext_vector_type(4), aligned(4)));  // align-4 float4

constexpr int NF = 169;
constexpr int NH = 128;

#define MFMA(a, b, c) __builtin_amdgcn_mfma_f32_16x16x32_bf16(a, b, c, 0, 0, 0)

// compiler + wave-level scheduling fence (no runtime cost; DS pipe is in-order per wave)
#define WFENCE() do { asm volatile("" ::: "memory"); \
                      __builtin_amdgcn_wave_barrier(); \
                      asm volatile("" ::: "memory"); } while (0)

__device__ inline unsigned short f2bf(float f) {
    union { __hip_bfloat16 h; unsigned short u; } c;
    c.h = __float2bfloat16(f);
    return c.u;
}

__device__ inline short8 cvt8(f4a v0, f4a v1) {
    short8 p;
    p[0] = (short)f2bf(v0[0]); p[1] = (short)f2bf(v0[1]);
    p[2] = (short)f2bf(v0[2]); p[3] = (short)f2bf(v0[3]);
    p[4] = (short)f2bf(v1[0]); p[5] = (short)f2bf(v1[1]);
    p[6] = (short)f2bf(v1[2]); p[7] = (short)f2bf(v1[3]);
    return p;
}

// LDS map (143872 B, one block/CU):
//   [0, 86528):        8 per-wave arenas of 10816 B:
//        pool [4 kg][64 rows][8] bf16 (4096 B)  -> dead after A1-frag reads
//        h    [16 kg][16 rows][8] bf16 (4096 B) -> per-mt, dead after A2 reads
//        stage[16][169] f32 (10816 B)           -> per-mt, aliases pool+h (both dead)
//   [86528, 131584):   w2g [16 kg][176 rows][8] bf16 (45056 B, rows>=169 zero)
//   [131584, 143872):  w1g [8 kg][128 rows][8] bf16 (12288 B, k>=36 zero)
// Single __syncthreads after weight staging; all later sync is wave-private.
__global__ __launch_bounds__(512, 2) void fused_v6(
    const float* __restrict__ x,
    const float* __restrict__ w1,
    const float* __restrict__ b1,
    const float* __restrict__ w2,
    const float* __restrict__ b2,
    float* __restrict__ out)
{
    __shared__ __align__(16) char smem[143872];
    unsigned short* w2g = (unsigned short*)(smem + 86528);
    unsigned short* w1g = (unsigned short*)(smem + 131584);

    const int tid  = threadIdx.x;
    const int wid  = tid >> 6;
    const int lane = tid & 63;
    const int lr   = lane & 15;
    const int hi   = lane >> 4;

    char* arena = smem + wid * 10816;
    unsigned short* pool  = (unsigned short*)arena;   // [4][64][8]
    unsigned short* hs    = (unsigned short*)arena;   // [16][16][8]
    float*          stage = (float*)arena;            // [16][169]

    // ---------------- cooperative weight staging ----------------
    #pragma unroll
    for (int it = 0; it < 6; ++it) {
        const int c = tid + it * 512;            // c = kg*176 + row
        if (c < 2816) {
            const int kg  = c / 176;
            const int row = c - kg * 176;
            short8 pk = {0, 0, 0, 0, 0, 0, 0, 0};
            if (row < NF) {
                f4a v0 = *(const f4a*)(w2 + row * NH + kg * 8);
                f4a v1 = *(const f4a*)(w2 + row * NH + kg * 8 + 4);
                pk = cvt8(v0, v1);
            }
            *(short8*)(w2g + c * 8) = pk;
        }
    }
    #pragma unroll
    for (int it = 0; it < 2; ++it) {
        const int c  = tid + it * 512;           // c = kg*128 + n
        const int kg = c >> 7, n = c & 127;
        short8 pk = {0, 0, 0, 0, 0, 0, 0, 0};
        if (kg < 4) {
            f4a v0 = *(const f4a*)(w1 + n * 36 + kg * 8);
            f4a v1 = *(const f4a*)(w1 + n * 36 + kg * 8 + 4);
            pk = cvt8(v0, v1);
        } else if (kg == 4) {
            f4a v0 = *(const f4a*)(w1 + n * 36 + 32);   // k = 32..35
            pk[0] = (short)f2bf(v0[0]); pk[1] = (short)f2bf(v0[1]);
            pk[2] = (short)f2bf(v0[2]); pk[3] = (short)f2bf(v0[3]);
        }
        *(short8*)(w1g + c * 8) = pk;
    }
    __syncthreads();   // the ONLY block barrier

    // ---------------- per-thread pooling (row = blk*512 + wid*64 + lane) ----------------
    const long rowBaseW = (long)blockIdx.x * 512 + wid * 64;
    const float* __restrict__ xr = x + (rowBaseW + lane) * NF;

    float f[169];
    #pragma unroll
    for (int i = 0; i < 42; ++i) {
        f4a v = *(const f4a*)(xr + i * 4);
        f[4*i+0] = v[0]; f[4*i+1] = v[1]; f[4*i+2] = v[2]; f[4*i+3] = v[3];
    }
    f[168] = xr[168];

    float pooled[36];
    #pragma unroll
    for (int i = 0; i < 6; ++i) {
        float cs[13];
        #pragma unroll
        for (int c = 0; c < 13; ++c) {
            float s = 0.0f;
            #pragma unroll
            for (int rr = 0; rr < 3; ++rr) {
                const int idx = (2 * i + rr) * 14 + c;   // compile-time
                if (idx < NF) s += f[idx];               // zero-pad region
            }
            cs[c] = s;
        }
        #pragma unroll
        for (int j = 0; j < 6; ++j) {
            const float s = cs[2*j] + cs[2*j+1] + cs[2*j+2];
            pooled[i * 6 + j] = fmaxf(s * (1.0f / 9.0f), 0.0f);
        }
    }

    // pack pooled -> 18 dwords (2 bf16 each)
    unsigned int pd[18];
    #pragma unroll
    for (int i = 0; i < 18; ++i) {
        unsigned int lo = f2bf(pooled[2 * i]);
        unsigned int hi2 = f2bf(pooled[2 * i + 1]);
        pd[i] = lo | (hi2 << 16);
    }

    // k=0..31 -> wave-private pool LDS
    #pragma unroll
    for (int g = 0; g < 4; ++g) {
        union { short8 s; unsigned int u[4]; } pk;
        pk.u[0] = pd[g*4+0]; pk.u[1] = pd[g*4+1];
        pk.u[2] = pd[g*4+2]; pk.u[3] = pd[g*4+3];
        *(short8*)(pool + (g * 64 + lane) * 8) = pk.s;
    }
    WFENCE();

    // ---------------- A1 fragments ----------------
    // ks=0 (k 0..31) from pool; ks=1 (k 32..63): only hi==0 lanes carry k=32..35 (via bpermute)
    short8 af0[4], af1[4];
    #pragma unroll
    for (int mt = 0; mt < 4; ++mt) {
        af0[mt] = *(const short8*)(pool + (hi * 64 + mt * 16 + lr) * 8);
        const int bidx = (mt * 16 + lr) * 4;
        const unsigned int p16 = (unsigned int)__builtin_amdgcn_ds_bpermute(bidx, (int)pd[16]);
        const unsigned int p17 = (unsigned int)__builtin_amdgcn_ds_bpermute(bidx, (int)pd[17]);
        union { short8 s; unsigned int u[4]; } a1;
        a1.u[0] = (hi == 0) ? p16 : 0u;
        a1.u[1] = (hi == 0) ? p17 : 0u;
        a1.u[2] = 0u; a1.u[3] = 0u;
        af1[mt] = a1.s;
    }
    WFENCE();   // pool reads complete; arena reusable for h/stage

    // ---------------- per-lane weight fragments / biases (persistent) ----------------
    short8 b1f[8][2];
    #pragma unroll
    for (int nt = 0; nt < 8; ++nt) {
        b1f[nt][0] = *(const short8*)(w1g + ((0 * 4 + hi) * 128 + nt * 16 + lr) * 8);
        b1f[nt][1] = *(const short8*)(w1g + ((1 * 4 + hi) * 128 + nt * 16 + lr) * 8);
    }
    float b1v[8];
    #pragma unroll
    for (int nt = 0; nt < 8; ++nt) b1v[nt] = b1[nt * 16 + lr];
    float b2v[11];
    #pragma unroll
    for (int t = 0; t < 11; ++t) {
        const int o = t * 16 + lr;
        b2v[t] = (o < NF) ? b2[o] : 0.0f;
    }

    // ---------------- wave-private m-tile loop: GEMM1 -> GEMM2 -> store ----------------
    #pragma unroll 1
    for (int mt = 0; mt < 4; ++mt) {
        // GEMM1: h-tile [16 rows x 128] = relu(pooled @ w1^T + b1)
        #pragma unroll
        for (int nt = 0; nt < 8; ++nt) {
            f32x4 c = {0.f, 0.f, 0.f, 0.f};
            c = MFMA(af0[mt], b1f[nt][0], c);
            c = MFMA(af1[mt], b1f[nt][1], c);
            const int g2 = 2 * nt + (lr >> 3);
            const int e  = lr & 7;
            #pragma unroll
            for (int r = 0; r < 4; ++r) {
                const float v = fmaxf(c[r] + b1v[nt], 0.0f);
                hs[(g2 * 16 + hi * 4 + r) * 8 + e] = f2bf(v);
            }
        }
        asm volatile("s_waitcnt lgkmcnt(0)" ::: "memory");
        WFENCE();   // h-tile visible

        short8 a2[4];
        #pragma unroll
        for (int ks = 0; ks < 4; ++ks)
            a2[ks] = *(const short8*)(hs + ((ks * 4 + hi) * 16 + lr) * 8);
        WFENCE();   // a2 reads issued before stage overwrites (in-order DS)

        // GEMM2: acc[t] over 11 output tiles, w2 frags transient from LDS
        f32x4 acc[11];
        #pragma unroll
        for (int t = 0; t < 11; ++t)
            acc[t] = (f32x4){b2v[t], b2v[t], b2v[t], b2v[t]};
        #pragma unroll
        for (int ks = 0; ks < 4; ++ks) {
            #pragma unroll
            for (int t = 0; t < 11; ++t) {
                short8 wf = *(const short8*)(w2g + ((ks * 4 + hi) * 176 + t * 16 + lr) * 8);
                acc[t] = MFMA(a2[ks], wf, acc[t]);
            }
        }

        // stage [16][169] f32 (aliases pool+h, both dead)
        #pragma unroll
        for (int t = 0; t < 11; ++t) {
            const int o = t * 16 + lr;
            if (t < 10 || o < NF) {
                #pragma unroll
                for (int r = 0; r < 4; ++r)
                    stage[(hi * 4 + r) * NF + o] = acc[t][r];
            }
        }
        asm volatile("s_waitcnt lgkmcnt(0)" ::: "memory");
        WFENCE();   // stage complete

        // coalesced store of 16 rows (2704 f32 = 676 float4)
        float* op = out + (rowBaseW + mt * 16) * NF;
        #pragma unroll
        for (int it = 0; it < 11; ++it) {
            const int idx = lane + it * 64;
            if (idx < 676) {
                f32x4 v = *(const f32x4*)(stage + idx * 4);
                *(f32x4*)(op + idx * 4) = v;
            }
        }
        WFENCE();   // stage reads issued before next mt's h writes (in-order DS)
    }
}

extern "C" void kernel_launch(void* const* d_in, const int* in_sizes, int n_in,
                              void* d_out, int out_size, void* d_ws, size_t ws_size,
                              hipStream_t stream) {
    const float* x  = (const float*)d_in[0];
    const float* w1 = (const float*)d_in[1];
    const float* b1 = (const float*)d_in[2];
    const float* w2 = (const float*)d_in[3];
    const float* b2 = (const float*)d_in[4];
    float* out = (float*)d_out;

    const int rows = in_sizes[0] / NF;      // 131072
    const int blocks = rows / 512;          // 256 = one per CU
    fused_v6<<<blocks, 512, 0, stream>>>(x, w1, b1, w2, b2, out);
}

// Round 7
// 41.020 us; speedup vs baseline: 2.2255x; 1.5848x over previous
//
#include <hip/hip_runtime.h>
#include <hip/hip_bf16.h>

typedef __attribute__((ext_vector_type(8))) short short8;
typedef __attribute__((ext_vector_type(4))) float f32x4;
typedef float f4a __attribute__((ext_vector_type(4), aligned(4)));  // align-4 float4

constexpr int NF = 169;
constexpr int NH = 128;

#define MFMA(a, b, c) __builtin_amdgcn_mfma_f32_16x16x32_bf16(a, b, c, 0, 0, 0)

__device__ inline unsigned short f2bf(float f) {
    union { __hip_bfloat16 h; unsigned short u; } c;
    c.h = __float2bfloat16(f);
    return c.u;
}

// Block barrier that drains ONLY the LDS pipe (lgkmcnt), never vmcnt.
// All cross-wave deps in this kernel are through LDS; global stores are
// fire-and-forget. __syncthreads would add s_waitcnt vmcnt(0) = per-iteration
// HBM store drain (the m97 barrier-drain problem).
__device__ inline void block_sync_lds() {
    __builtin_amdgcn_sched_barrier(0);
    asm volatile("s_waitcnt lgkmcnt(0)" ::: "memory");
    __builtin_amdgcn_sched_barrier(0);
    __builtin_amdgcn_s_barrier();
    __builtin_amdgcn_sched_barrier(0);
}

// LDS map (78336 B total, 16B aligned):
//  [0, 65536):      pool_g[8][256][8] bf16 (32768 B)  --later aliased by--> h_g[16][256][8] bf16
//  [65536, 77824):  w1g[8][128][8] bf16 (12288 B)     --later aliased by--> stage[16][169] f32 (10816 B)
//  [77824, 78336):  b1s[128] f32
__global__ __launch_bounds__(256, 2) void fused_v7(
    const float* __restrict__ x,
    const float* __restrict__ w1,
    const float* __restrict__ b1,
    const float* __restrict__ w2,
    const float* __restrict__ b2,
    float* __restrict__ out)
{
    __shared__ __align__(16) char smem[78336];
    unsigned short* pool_g = (unsigned short*)smem;            // [8][256][8]
    unsigned short* h_g    = (unsigned short*)smem;            // [16][256][8]
    unsigned short* w1g    = (unsigned short*)(smem + 65536);  // [8][128][8]
    float*          stage  = (float*)(smem + 65536);           // [16][169]
    float*          b1s    = (float*)(smem + 77824);           // [128]

    const int tid  = threadIdx.x;
    const int wid  = tid >> 6;
    const int lane = tid & 63;
    const int lr   = lane & 15;
    const int hi   = lane >> 4;

    // ---------------- stage w1 -> w1g (bf16, k zero-padded 36->64), b1 -> b1s ----------------
    #pragma unroll
    for (int it = 0; it < 4; ++it) {
        const int idx = tid + it * 256;   // 0..1023 = n*8 + g
        const int n = idx >> 3, g = idx & 7;
        short8 pk;
        #pragma unroll
        for (int j = 0; j < 8; ++j) {
            const int k = g * 8 + j;
            pk[j] = (short)f2bf(k < 36 ? w1[n * 36 + k] : 0.0f);
        }
        *(short8*)(w1g + (g * 128 + n) * 8) = pk;
    }
    if (tid < 128) b1s[tid] = b1[tid];

    // ---------------- per-thread pooling of row (blk*256 + tid) ----------------
    const long row = (long)blockIdx.x * 256 + tid;
    const float* __restrict__ xr = x + row * NF;

    float f[169];
    #pragma unroll
    for (int i = 0; i < 42; ++i) {
        f4a v = *(const f4a*)(xr + i * 4);
        f[4*i+0] = v[0]; f[4*i+1] = v[1]; f[4*i+2] = v[2]; f[4*i+3] = v[3];
    }
    f[168] = xr[168];

    float pooled[36];
    #pragma unroll
    for (int i = 0; i < 6; ++i) {
        float cs[13];
        #pragma unroll
        for (int c = 0; c < 13; ++c) {
            float s = 0.0f;
            #pragma unroll
            for (int rr = 0; rr < 3; ++rr) {
                const int idx = (2 * i + rr) * 14 + c;   // compile-time
                if (idx < NF) s += f[idx];               // pad region = 0
            }
            cs[c] = s;
        }
        #pragma unroll
        for (int j = 0; j < 6; ++j) {
            const float s = cs[2*j] + cs[2*j+1] + cs[2*j+2];
            pooled[i * 6 + j] = fmaxf(s * (1.0f / 9.0f), 0.0f);
        }
    }

    // write pooled row to pool_g, k-groups of 8, zeros for k >= 36
    #pragma unroll
    for (int g = 0; g < 8; ++g) {
        short8 pk;
        #pragma unroll
        for (int j = 0; j < 8; ++j) {
            const int k = g * 8 + j;
            pk[j] = (k < 36) ? (short)f2bf(pooled[k]) : (short)0;
        }
        *(short8*)(pool_g + (g * 256 + tid) * 8) = pk;
    }
    block_sync_lds();   // (1) pool_g complete

    // ---------------- A1 fragments (wave's 4 m-tiles) + w2/b2 fragments to registers ----------------
    short8 afrag[4][2];
    #pragma unroll
    for (int mt = 0; mt < 4; ++mt)
        #pragma unroll
        for (int ks = 0; ks < 2; ++ks) {
            const int g = ks * 4 + hi;
            afrag[mt][ks] = *(const short8*)(pool_g + (g * 256 + wid * 64 + mt * 16 + lr) * 8);
        }

    const int nOt = (wid < 3) ? 3 : 2;   // ot = wid + 4t, 11 total
    short8 wfrag[3][4];
    float  bias2[3];
    #pragma unroll
    for (int t = 0; t < 3; ++t) {
        const int ot = wid + 4 * t;
        const int o  = ot * 16 + lr;
        const bool valid = (t < nOt) && (o < NF);
        bias2[t] = valid ? b2[o] : 0.0f;
        #pragma unroll
        for (int ks = 0; ks < 4; ++ks) {
            short8 pk = {0, 0, 0, 0, 0, 0, 0, 0};
            if (valid) {
                const float* wp = w2 + o * NH + ks * 32 + hi * 8;
                #pragma unroll
                for (int j = 0; j < 8; ++j) pk[j] = (short)f2bf(wp[j]);
            }
            wfrag[t][ks] = pk;
        }
    }
    block_sync_lds();   // (2) all a-frags read; pool region dead -> h_g may overwrite

    // ---------------- GEMM1: h = relu(pooled @ w1^T + b1), written to h_g ----------------
    short8 b1f[8][2];
    #pragma unroll
    for (int nt = 0; nt < 8; ++nt)
        #pragma unroll
        for (int ks = 0; ks < 2; ++ks) {
            const int g = ks * 4 + hi;
            b1f[nt][ks] = *(const short8*)(w1g + (g * 128 + nt * 16 + lr) * 8);
        }
    float bias1[8];
    #pragma unroll
    for (int nt = 0; nt < 8; ++nt) bias1[nt] = b1s[nt * 16 + lr];

    #pragma unroll
    for (int mt = 0; mt < 4; ++mt) {
        #pragma unroll
        for (int nt = 0; nt < 8; ++nt) {
            f32x4 c = {0.f, 0.f, 0.f, 0.f};
            c = MFMA(afrag[mt][0], b1f[nt][0], c);
            c = MFMA(afrag[mt][1], b1f[nt][1], c);
            const int g = 2 * nt + (lr >> 3);
            const int e = lr & 7;
            #pragma unroll
            for (int r = 0; r < 4; ++r) {
                const float v = fmaxf(c[r] + bias1[nt], 0.0f);
                const int rw = wid * 64 + mt * 16 + hi * 4 + r;
                h_g[(g * 256 + rw) * 8 + e] = (unsigned short)f2bf(v);
            }
        }
    }
    block_sync_lds();   // (3) h_g complete; w1g dead -> stage usable

    // ---------------- GEMM2 (ot-split, w2 in regs) + staged coalesced stores ----------------
    const long blkRowBase = (long)blockIdx.x * 256;
    #pragma unroll 1
    for (int mt = 0; mt < 16; ++mt) {
        short8 a2[4];
        #pragma unroll
        for (int ks = 0; ks < 4; ++ks) {
            const int g = ks * 4 + hi;
            a2[ks] = *(const short8*)(h_g + (g * 256 + mt * 16 + lr) * 8);
        }
        f32x4 acc[3];
        #pragma unroll
        for (int t = 0; t < 3; ++t) {
            f32x4 c = {0.f, 0.f, 0.f, 0.f};
            #pragma unroll
            for (int ks = 0; ks < 4; ++ks)
                c = MFMA(a2[ks], wfrag[t][ks], c);
            acc[t] = c;
        }
        #pragma unroll
        for (int t = 0; t < 3; ++t) {
            const int ot = wid + 4 * t;
            const int o  = ot * 16 + lr;
            if (t < nOt && o < NF) {
                #pragma unroll
                for (int r = 0; r < 4; ++r)
                    stage[(hi * 4 + r) * NF + o] = acc[t][r] + bias2[t];
            }
        }
        block_sync_lds();   // stage complete for this m-tile (LDS-only drain)

        float* op = out + (blkRowBase + mt * 16) * NF;
        #pragma unroll
        for (int it = 0; it < 3; ++it) {
            const int i = tid + it * 256;
            if (i < 676) {                      // 16*169/4 float4s
                f32x4 v = *(const f32x4*)(stage + 4 * i);
                *(f32x4*)(op + 4 * i) = v;
            }
        }
        block_sync_lds();   // stage ds_reads retired; stores stay in flight (no vmcnt drain)
    }
}

extern "C" void kernel_launch(void* const* d_in, const int* in_sizes, int n_in,
                              void* d_out, int out_size, void* d_ws, size_t ws_size,
                              hipStream_t stream) {
    const float* x  = (const float*)d_in[0];
    const float* w1 = (const float*)d_in[1];
    const float* b1 = (const float*)d_in[2];
    const float* w2 = (const float*)d_in[3];
    const float* b2 = (const float*)d_in[4];
    float* out = (float*)d_out;

    const int rows = in_sizes[0] / NF;      // 131072
    const int blocks = rows / 256;          // 512
    fused_v7<<<blocks, 256, 0, stream>>>(x, w1, b1, w2, b2, out);
}